// Round 8
// baseline (832.242 us; speedup 1.0000x reference)
//
#include <hip/hip_runtime.h>
#include <hip/hip_bf16.h>

constexpr int Nn = 100000;   // nodes
constexpr int Ee = 1600000;  // edges
constexpr int Fd = 128;      // in features
constexpr int Dd = 64;       // out features
constexpr float ALPHA = 0.2f;

constexpr int BSH    = 8;                              // 256 rows per bucket
constexpr int NBUCK  = (Nn + (1 << BSH) - 1) >> BSH;   // 391
constexpr int BSLACK = 8192;                           // slack entries per bucket (mean fill 4096)
constexpr int BCAP   = 24;                             // LDS entries per bucket per block
constexpr int BINB   = 256;                            // edge_bin blocks (6250 edges each, mean 16/bucket)

typedef __attribute__((ext_vector_type(8))) short bf16x8;   // 8 bf16 (4 VGPRs)
typedef __attribute__((ext_vector_type(4))) float f32x4;    // MFMA accumulator

__device__ __forceinline__ unsigned short f2bf(float f) {  // RTNE
    unsigned int u = __float_as_uint(f);
    u += 0x7fffu + ((u >> 16) & 1u);
    return (unsigned short)(u >> 16);
}
__device__ __forceinline__ float bf2f(unsigned short s) {
    return __uint_as_float((unsigned int)s << 16);
}

// ---------------- MFMA GEMM: h(bf16) = x @ W, ar = h@a_row, ac = h@a_col --------
__global__ __launch_bounds__(256, 4) void gemm_scores(
    const float* __restrict__ x, const float* __restrict__ W,
    const float* __restrict__ a_row, const float* __restrict__ a_col,
    unsigned short* __restrict__ h, float* __restrict__ ar, float* __restrict__ ac)
{
    constexpr int HP = 136;              // LDS pitch (bf16): 2-way bank alias (free)
    __shared__ unsigned short xs[64 * HP];   // x tile, bf16 [node][k]
    __shared__ unsigned short wt[64 * HP];   // W^T,   bf16 [d][k]
    __shared__ float as_[2 * Dd];            // a_row | a_col

    const int tid = threadIdx.x;

    #pragma unroll 4
    for (int it = 0; it < 32; ++it) {
        int idx = tid + 256 * it;
        int k = idx >> 6, d = idx & 63;
        wt[d * HP + k] = f2bf(W[idx]);
    }
    if (tid < 2 * Dd) as_[tid] = (tid < Dd) ? a_row[tid] : a_col[tid - Dd];

    const int node0 = blockIdx.x * 64;
    const float4* xg = (const float4*)(x + (size_t)node0 * Fd);
    #pragma unroll
    for (int it = 0; it < 8; ++it) {
        int g  = tid + 256 * it;
        int nd = g >> 5, k4 = g & 31;
        float4 v = make_float4(0.f, 0.f, 0.f, 0.f);
        if (node0 + nd < Nn) v = xg[g];
        ushort4 bv = make_ushort4(f2bf(v.x), f2bf(v.y), f2bf(v.z), f2bf(v.w));
        *(ushort4*)&xs[nd * HP + k4 * 4] = bv;
    }
    __syncthreads();

    const int lane = tid & 63;
    const int wid  = tid >> 6;
    const int nlo  = lane & 15;
    const int quad = lane >> 4;

    f32x4 acc[4] = {{0.f,0.f,0.f,0.f},{0.f,0.f,0.f,0.f},{0.f,0.f,0.f,0.f},{0.f,0.f,0.f,0.f}};
    const unsigned short* xrow = &xs[(wid * 16 + nlo) * HP + quad * 8];

    #pragma unroll
    for (int ks = 0; ks < 4; ++ks) {
        bf16x8 a = *(const bf16x8*)(xrow + ks * 32);
        #pragma unroll
        for (int t = 0; t < 4; ++t) {
            bf16x8 b = *(const bf16x8*)&wt[(t * 16 + nlo) * HP + quad * 8 + ks * 32];
            acc[t] = __builtin_amdgcn_mfma_f32_16x16x32_bf16(a, b, acc[t], 0, 0, 0);
        }
    }

    #pragma unroll
    for (int r = 0; r < 4; ++r) {
        int node = node0 + wid * 16 + quad * 4 + r;
        float pr = 0.f, pc = 0.f;
        #pragma unroll
        for (int t = 0; t < 4; ++t) {
            float v = acc[t][r];
            pr = fmaf(v, as_[t * 16 + nlo], pr);
            pc = fmaf(v, as_[Dd + t * 16 + nlo], pc);
        }
        #pragma unroll
        for (int o = 1; o < 16; o <<= 1) {
            pr += __shfl_xor(pr, o, 64);
            pc += __shfl_xor(pc, o, 64);
        }
        if (node < Nn) {
            #pragma unroll
            for (int t = 0; t < 4; ++t)
                h[(size_t)node * Dd + t * 16 + nlo] = f2bf(acc[t][r]);
            if (nlo == 0) { ar[node] = pr; ac[node] = pc; }
        }
    }
}

// ---------------- bucket write-pointer init ----------------
__global__ void bwp_init(int* __restrict__ bwp)
{
    int b = blockIdx.x * 256 + threadIdx.x;
    if (b < NBUCK) bwp[b] = b * BSLACK;
}

// ---------------- edge_bin: LDS-binned staging of PACKED edges --------------
// entry = ((r & 255) << 17) | c   (c < 2^17, rl 8 bits -> 25 bits total)
__global__ __launch_bounds__(256, 2) void edge_bin(
    const int* __restrict__ rows, const int* __restrict__ cols,
    int* __restrict__ bwp, unsigned int* __restrict__ binned)
{
    __shared__ unsigned int buf[NBUCK * BCAP];   // 37.5 KB
    __shared__ int lcnt[NBUCK];
    __shared__ int lbase[NBUCK];

    const int tid = threadIdx.x;
    for (int b = tid; b < NBUCK; b += 256) lcnt[b] = 0;
    __syncthreads();

    const int per = (Ee + BINB - 1) / BINB;   // 6250
    const int e0 = blockIdx.x * per;
    const int e1 = min(e0 + per, Ee);

    for (int base = e0; base < e1; base += 256) {
        int e = base + tid;
        if (e < e1) {
            int r = rows[e], c = cols[e];
            int b = r >> BSH;
            unsigned int pe = ((unsigned)(r & 255) << 17) | (unsigned)c;
            int pos = atomicAdd(&lcnt[b], 1);
            if (pos < BCAP) buf[b * BCAP + pos] = pe;
            else {  // ~2% spill: direct append
                int slot = atomicAdd(&bwp[b], 1);
                if (slot < (b + 1) * BSLACK) binned[slot] = pe;
            }
        }
    }
    __syncthreads();
    for (int b = tid; b < NBUCK; b += 256)
        lbase[b] = atomicAdd(&bwp[b], min(lcnt[b], BCAP));
    __syncthreads();
    int w = tid >> 6, lane = tid & 63;
    for (int b = w; b < NBUCK; b += 4) {
        int cnt = min(lcnt[b], BCAP);
        int gb = lbase[b];
        for (int i = lane; i < cnt; i += 64)
            binned[gb + i] = buf[b * BCAP + i];
    }
}

// ------------- spmm_half: fused softmax-weights + SpMM, no CSR needed -------------
// Block = half a bucket (128 nodes). Unordered edges accumulate into an LDS
// fp32 tile via ds_add_f32 (pitch 65 spreads banks; col 64 holds wsum).
__global__ __launch_bounds__(256, 3) void spmm_half(
    const unsigned int* __restrict__ binned, const int* __restrict__ bwp,
    const float* __restrict__ ar, const float* __restrict__ ac,
    const unsigned short* __restrict__ h, float* __restrict__ out)
{
    constexpr int P = 65;
    __shared__ float accum[128 * P];   // 33.28 KB; accum[rl*P+64] = wsum
    __shared__ float lar[128];
    __shared__ float linv[128];

    const int tid   = threadIdx.x;
    const int b     = blockIdx.x >> 1;
    const int half  = blockIdx.x & 1;
    const int node0 = (b << BSH) + half * 128;
    const int base  = b * BSLACK;
    const int n     = min(bwp[b] - base, BSLACK);

    for (int i = tid; i < 128 * P; i += 256) accum[i] = 0.f;
    if (tid < 128) {
        int node = node0 + tid;
        lar[tid] = (node < Nn) ? ar[node] : 0.f;
    }
    __syncthreads();

    for (int s = tid; s < n; s += 256) {
        unsigned int pe = binned[base + s];
        int rl = (int)(pe >> 17) - half * 128;
        if ((unsigned)rl < 128u) {
            int c = (int)(pe & 0x1FFFFu);
            float sc = lar[rl] + ac[c];
            sc = sc > 0.f ? sc : ALPHA * sc;
            float ex = __expf(sc);
            float* arow = &accum[rl * P];
            atomicAdd(&arow[64], ex);
            const uint4* hp = (const uint4*)(h + (size_t)c * Dd);
            #pragma unroll
            for (int q = 0; q < 4; ++q) {
                uint4 v = hp[q];   // 8 bf16
                unsigned int uu[4] = {v.x, v.y, v.z, v.w};
                #pragma unroll
                for (int m = 0; m < 4; ++m) {
                    float flo = __uint_as_float(uu[m] << 16);
                    float fhi = __uint_as_float(uu[m] & 0xFFFF0000u);
                    atomicAdd(&arow[q * 8 + m * 2 + 0], ex * flo);
                    atomicAdd(&arow[q * 8 + m * 2 + 1], ex * fhi);
                }
            }
            #pragma unroll
            for (int q = 4; q < 8; ++q) {
                uint4 v = hp[q];
                unsigned int uu[4] = {v.x, v.y, v.z, v.w};
                #pragma unroll
                for (int m = 0; m < 4; ++m) {
                    float flo = __uint_as_float(uu[m] << 16);
                    float fhi = __uint_as_float(uu[m] & 0xFFFF0000u);
                    atomicAdd(&arow[q * 8 + m * 2 + 0], ex * flo);
                    atomicAdd(&arow[q * 8 + m * 2 + 1], ex * fhi);
                }
            }
        }
    }
    __syncthreads();

    if (tid < 128) {
        float wsv = accum[tid * P + 64];
        linv[tid] = (wsv > 0.f) ? 1.f / wsv : 0.f;
    }
    __syncthreads();

    for (int i = tid; i < 128 * Dd; i += 256) {
        int rl = i >> 6, col = i & 63;
        int node = node0 + rl;
        if (node < Nn)
            out[(size_t)node * Dd + col] = accum[rl * P + col] * linv[rl];
    }
}

// ---------------- launch ----------------
extern "C" void kernel_launch(void* const* d_in, const int* in_sizes, int n_in,
                              void* d_out, int out_size, void* d_ws, size_t ws_size,
                              hipStream_t stream)
{
    const float* x     = (const float*)d_in[0];
    const int*   rows  = (const int*)d_in[1];
    const int*   cols  = (const int*)d_in[2];
    const float* W     = (const float*)d_in[3];
    const float* a_row = (const float*)d_in[4];
    const float* a_col = (const float*)d_in[5];
    float* out = (float*)d_out;

    char* ws = (char*)d_ws;
    size_t o = 0;
    unsigned short* h = (unsigned short*)(ws + o); o += (size_t)Nn * Dd * 2;  // 12.8 MB
    float* ar   = (float*)(ws + o); o += (size_t)Nn * 4;
    float* ac   = (float*)(ws + o); o += (size_t)Nn * 4;
    int*   bwp  = (int*)(ws + o);   o += 512 * 4;
    unsigned int* binned = (unsigned int*)(ws + o); o += (size_t)NBUCK * BSLACK * 4; // 12.8 MB

    bwp_init<<<2, 256, 0, stream>>>(bwp);
    edge_bin<<<BINB, 256, 0, stream>>>(rows, cols, bwp, binned);
    gemm_scores<<<(Nn + 63) / 64, 256, 0, stream>>>(x, W, a_row, a_col, h, ar, ac);
    spmm_half<<<NBUCK * 2, 256, 0, stream>>>(binned, bwp, ar, ac, h, out);
}

// Round 9
// 194.211 us; speedup vs baseline: 4.2853x; 4.2853x over previous
//
#include <hip/hip_runtime.h>
#include <hip/hip_bf16.h>

constexpr int Nn = 100000;   // nodes
constexpr int Ee = 1600000;  // edges
constexpr int Fd = 128;      // in features
constexpr int Dd = 64;       // out features
constexpr float ALPHA = 0.2f;

constexpr int BSH    = 8;                              // 256 rows per bucket
constexpr int NBUCK  = (Nn + (1 << BSH) - 1) >> BSH;   // 391
constexpr int BSLACK = 8192;                           // slack entries per bucket (mean fill 4096)
constexpr int BCAP   = 24;                             // LDS entries per bucket per edge_bin block
constexpr int BINB   = 512;                            // edge_bin blocks (3125 edges each)
constexpr int HCAP   = 2688;                           // spmm per-half-bucket LDS edge cap (mean 2048, +14 sigma)

typedef __attribute__((ext_vector_type(8))) short bf16x8;   // 8 bf16 (4 VGPRs)
typedef __attribute__((ext_vector_type(4))) float f32x4;    // MFMA accumulator

__device__ __forceinline__ unsigned short f2bf(float f) {  // RTNE
    unsigned int u = __float_as_uint(f);
    u += 0x7fffu + ((u >> 16) & 1u);
    return (unsigned short)(u >> 16);
}
__device__ __forceinline__ float bf2f(unsigned short s) {
    return __uint_as_float((unsigned int)s << 16);
}

// ---------------- MFMA GEMM: h(bf16) = x @ W, ar = h@a_row, ac = h@a_col --------
__global__ __launch_bounds__(256, 4) void gemm_scores(
    const float* __restrict__ x, const float* __restrict__ W,
    const float* __restrict__ a_row, const float* __restrict__ a_col,
    unsigned short* __restrict__ h, float* __restrict__ ar, float* __restrict__ ac)
{
    constexpr int HP = 136;              // LDS pitch (bf16): 2-way bank alias (free)
    __shared__ unsigned short xs[64 * HP];   // x tile, bf16 [node][k]
    __shared__ unsigned short wt[64 * HP];   // W^T,   bf16 [d][k]
    __shared__ float as_[2 * Dd];            // a_row | a_col

    const int tid = threadIdx.x;

    #pragma unroll 4
    for (int it = 0; it < 32; ++it) {
        int idx = tid + 256 * it;
        int k = idx >> 6, d = idx & 63;
        wt[d * HP + k] = f2bf(W[idx]);
    }
    if (tid < 2 * Dd) as_[tid] = (tid < Dd) ? a_row[tid] : a_col[tid - Dd];

    const int node0 = blockIdx.x * 64;
    const float4* xg = (const float4*)(x + (size_t)node0 * Fd);
    #pragma unroll
    for (int it = 0; it < 8; ++it) {
        int g  = tid + 256 * it;
        int nd = g >> 5, k4 = g & 31;
        float4 v = make_float4(0.f, 0.f, 0.f, 0.f);
        if (node0 + nd < Nn) v = xg[g];
        ushort4 bv = make_ushort4(f2bf(v.x), f2bf(v.y), f2bf(v.z), f2bf(v.w));
        *(ushort4*)&xs[nd * HP + k4 * 4] = bv;
    }
    __syncthreads();

    const int lane = tid & 63;
    const int wid  = tid >> 6;
    const int nlo  = lane & 15;
    const int quad = lane >> 4;

    f32x4 acc[4] = {{0.f,0.f,0.f,0.f},{0.f,0.f,0.f,0.f},{0.f,0.f,0.f,0.f},{0.f,0.f,0.f,0.f}};
    const unsigned short* xrow = &xs[(wid * 16 + nlo) * HP + quad * 8];

    #pragma unroll
    for (int ks = 0; ks < 4; ++ks) {
        bf16x8 a = *(const bf16x8*)(xrow + ks * 32);
        #pragma unroll
        for (int t = 0; t < 4; ++t) {
            bf16x8 b = *(const bf16x8*)&wt[(t * 16 + nlo) * HP + quad * 8 + ks * 32];
            acc[t] = __builtin_amdgcn_mfma_f32_16x16x32_bf16(a, b, acc[t], 0, 0, 0);
        }
    }

    #pragma unroll
    for (int r = 0; r < 4; ++r) {
        int node = node0 + wid * 16 + quad * 4 + r;
        float pr = 0.f, pc = 0.f;
        #pragma unroll
        for (int t = 0; t < 4; ++t) {
            float v = acc[t][r];
            pr = fmaf(v, as_[t * 16 + nlo], pr);
            pc = fmaf(v, as_[Dd + t * 16 + nlo], pc);
        }
        #pragma unroll
        for (int o = 1; o < 16; o <<= 1) {
            pr += __shfl_xor(pr, o, 64);
            pc += __shfl_xor(pc, o, 64);
        }
        if (node < Nn) {
            #pragma unroll
            for (int t = 0; t < 4; ++t)
                h[(size_t)node * Dd + t * 16 + nlo] = f2bf(acc[t][r]);
            if (nlo == 0) { ar[node] = pr; ac[node] = pc; }
        }
    }
}

// ---------------- bucket write-pointer init ----------------
__global__ void bwp_init(int* __restrict__ bwp)
{
    int b = blockIdx.x * 256 + threadIdx.x;
    if (b < NBUCK) bwp[b] = b * BSLACK;
}

// ---------------- edge_bin: LDS-binned staging of PACKED 4B edges --------------
// entry = ((r & 255) << 17) | c   (c < 2^17)
__global__ __launch_bounds__(256, 2) void edge_bin(
    const int* __restrict__ rows, const int* __restrict__ cols,
    int* __restrict__ bwp, unsigned int* __restrict__ binned)
{
    __shared__ unsigned int buf[NBUCK * BCAP];   // 37.5 KB
    __shared__ int lcnt[NBUCK];
    __shared__ int lbase[NBUCK];

    const int tid = threadIdx.x;
    for (int b = tid; b < NBUCK; b += 256) lcnt[b] = 0;
    __syncthreads();

    const int per = (Ee + BINB - 1) / BINB;   // 3125
    const int e0 = blockIdx.x * per;
    const int e1 = min(e0 + per, Ee);

    for (int base = e0; base < e1; base += 256) {
        int e = base + tid;
        if (e < e1) {
            int r = rows[e], c = cols[e];
            int b = r >> BSH;
            unsigned int pe = ((unsigned)(r & 255) << 17) | (unsigned)c;
            int pos = atomicAdd(&lcnt[b], 1);
            if (pos < BCAP) buf[b * BCAP + pos] = pe;
            else {  // rare spill: direct append
                int slot = atomicAdd(&bwp[b], 1);
                if (slot < (b + 1) * BSLACK) binned[slot] = pe;
            }
        }
    }
    __syncthreads();
    for (int b = tid; b < NBUCK; b += 256)
        lbase[b] = atomicAdd(&bwp[b], min(lcnt[b], BCAP));
    __syncthreads();
    int w = tid >> 6, lane = tid & 63;
    for (int b = w; b < NBUCK; b += 4) {
        int cnt = min(lcnt[b], BCAP);
        int gb = lbase[b];
        for (int i = lane; i < cnt; i += 64)
            binned[gb + i] = buf[b * BCAP + i];
    }
}

// ------------- spmm_fused: in-LDS CSR build + R7-style broadcast gather -------------
// Block = half-bucket (128 nodes). Count -> scan -> scatter ordered (col,ex)
// into LDS, then per-16-lane-group broadcast gather (identical to R7 spmm).
__global__ __launch_bounds__(256) void spmm_fused(
    const unsigned int* __restrict__ binned, const int* __restrict__ bwp,
    const float* __restrict__ ar, const float* __restrict__ ac,
    const unsigned short* __restrict__ h, float* __restrict__ out)
{
    __shared__ float2 lce[HCAP];     // 21 KB ordered (col, ex)
    __shared__ int   cnt[128];
    __shared__ int   wp[128];
    __shared__ int   loff[129];
    __shared__ float lar[128];
    __shared__ int   wsh[4];

    const int tid   = threadIdx.x;
    const int b     = blockIdx.x >> 1;
    const int half  = blockIdx.x & 1;
    const int node0 = (b << BSH) + half * 128;
    const int base  = b * BSLACK;
    const int n     = min(bwp[b] - base, BSLACK);

    if (tid < 128) {
        cnt[tid] = 0;
        int node = node0 + tid;
        lar[tid] = (node < Nn) ? ar[node] : 0.f;
    }
    __syncthreads();

    // pass 1: count this half's edges
    for (int s = tid; s < n; s += 256) {
        int rl = (int)(binned[base + s] >> 17) - half * 128;
        if ((unsigned)rl < 128u) atomicAdd(&cnt[rl], 1);
    }
    __syncthreads();

    // exclusive scan (256-wide, top half zero-padded)
    int v = (tid < 128) ? cnt[tid] : 0;
    int lane = tid & 63, w = tid >> 6;
    int incl = v;
    #pragma unroll
    for (int o = 1; o < 64; o <<= 1) {
        int y = __shfl_up(incl, o, 64);
        if (lane >= o) incl += y;
    }
    if (lane == 63) wsh[w] = incl;
    __syncthreads();
    int pre = 0;
    for (int j = 0; j < w; ++j) pre += wsh[j];
    int excl = pre + incl - v;
    if (tid < 128) { loff[tid] = excl; wp[tid] = excl; }
    if (tid == 128) loff[128] = excl;   // total (v=0 here)
    __syncthreads();

    // pass 2: LeakyReLU+exp, scatter ordered into LDS
    for (int s = tid; s < n; s += 256) {
        unsigned int pe = binned[base + s];
        int rl = (int)(pe >> 17) - half * 128;
        if ((unsigned)rl < 128u) {
            int c = (int)(pe & 0x1FFFFu);
            float sc = lar[rl] + ac[c];
            sc = sc > 0.f ? sc : ALPHA * sc;
            float ex = __expf(sc);
            int pos = atomicAdd(&wp[rl], 1);
            if (pos < HCAP) lce[pos] = make_float2(__int_as_float(c), ex);
        }
    }
    __syncthreads();

    // pass 3: broadcast gather (R7 structure), 8 nodes per 16-lane group
    const int grp = tid >> 4, lq = tid & 15;
    const ushort4* h4 = (const ushort4*)h;   // row = 16 ushort4
    #pragma unroll
    for (int i = 0; i < 8; ++i) {
        int rl = grp * 8 + i;
        int node = node0 + rl;
        if (node >= Nn) break;
        int s0 = loff[rl], s1 = loff[rl + 1];
        float4 acc = make_float4(0.f, 0.f, 0.f, 0.f);
        float wsum = 0.f;
        int j = s0;
        for (; j + 8 <= s1; j += 8) {
            float2 p[8];
            ushort4 hv[8];
            #pragma unroll
            for (int u = 0; u < 8; ++u) p[u] = lce[j + u];            // broadcast
            #pragma unroll
            for (int u = 0; u < 8; ++u)
                hv[u] = h4[(size_t)__float_as_int(p[u].x) * 16 + lq]; // 8 in flight
            #pragma unroll
            for (int u = 0; u < 8; ++u) {
                float wgt = p[u].y;
                wsum += wgt;
                acc.x = fmaf(wgt, bf2f(hv[u].x), acc.x);
                acc.y = fmaf(wgt, bf2f(hv[u].y), acc.y);
                acc.z = fmaf(wgt, bf2f(hv[u].z), acc.z);
                acc.w = fmaf(wgt, bf2f(hv[u].w), acc.w);
            }
        }
        for (; j < s1; ++j) {
            float2 p = lce[j];
            float wgt = p.y;
            wsum += wgt;
            ushort4 hv = h4[(size_t)__float_as_int(p.x) * 16 + lq];
            acc.x = fmaf(wgt, bf2f(hv.x), acc.x);
            acc.y = fmaf(wgt, bf2f(hv.y), acc.y);
            acc.z = fmaf(wgt, bf2f(hv.z), acc.z);
            acc.w = fmaf(wgt, bf2f(hv.w), acc.w);
        }
        float inv = (s1 > s0) ? 1.f / wsum : 0.f;
        float4 o = make_float4(acc.x * inv, acc.y * inv, acc.z * inv, acc.w * inv);
        ((float4*)out)[(size_t)node * 16 + lq] = o;
    }
}

// ---------------- launch ----------------
extern "C" void kernel_launch(void* const* d_in, const int* in_sizes, int n_in,
                              void* d_out, int out_size, void* d_ws, size_t ws_size,
                              hipStream_t stream)
{
    const float* x     = (const float*)d_in[0];
    const int*   rows  = (const int*)d_in[1];
    const int*   cols  = (const int*)d_in[2];
    const float* W     = (const float*)d_in[3];
    const float* a_row = (const float*)d_in[4];
    const float* a_col = (const float*)d_in[5];
    float* out = (float*)d_out;

    char* ws = (char*)d_ws;
    size_t o = 0;
    unsigned short* h = (unsigned short*)(ws + o); o += (size_t)Nn * Dd * 2;  // 12.8 MB
    float* ar   = (float*)(ws + o); o += (size_t)Nn * 4;
    float* ac   = (float*)(ws + o); o += (size_t)Nn * 4;
    int*   bwp  = (int*)(ws + o);   o += 512 * 4;
    unsigned int* binned = (unsigned int*)(ws + o); o += (size_t)NBUCK * BSLACK * 4; // 12.8 MB

    bwp_init<<<2, 256, 0, stream>>>(bwp);
    edge_bin<<<BINB, 256, 0, stream>>>(rows, cols, bwp, binned);
    gemm_scores<<<(Nn + 63) / 64, 256, 0, stream>>>(x, W, a_row, a_col, h, ar, ac);
    spmm_fused<<<NBUCK * 2, 256, 0, stream>>>(binned, bwp, ar, ac, h, out);
}